// Round 15
// baseline (115.070 us; speedup 1.0000x reference)
//
#include <hip/hip_runtime.h>

#define Bn 8
#define Tn 1024
#define Dn 768
#define Hn 12
#define HDn 64
#define D3 (3 * Dn)

typedef float f32x4 __attribute__((ext_vector_type(4)));
typedef short bf16x8 __attribute__((ext_vector_type(8)));
typedef unsigned short u16;

// softmax computed in exp2 domain: scale = (1/sqrt(64)) * log2(e)
#define SM_SCALE 0.18033688011112042f

__device__ __forceinline__ u16 f2b(float f) {
    unsigned u = __builtin_bit_cast(unsigned, f);
    u += 0x7fffu + ((u >> 16) & 1u);
    return (u16)(u >> 16);
}

__device__ __forceinline__ unsigned cvt_pk_bf16(float lo, float hi) {
    unsigned r;
    asm("v_cvt_pk_bf16_f32 %0, %1, %2" : "=v"(r) : "v"(lo), "v"(hi));
    return r;
}

__device__ __forceinline__ void async_lds16(void* lds, const void* g) {
    __builtin_amdgcn_global_load_lds(
        (const __attribute__((address_space(1))) unsigned int*)g,
        (__attribute__((address_space(3))) unsigned int*)lds, 16, 0, 0);
}

// ---------------------------------------------------------------------------
// fp32 -> bf16 elementwise convert, 8 elems/thread (n divisible by 8)
// ---------------------------------------------------------------------------
__global__ __launch_bounds__(256)
void conv_bf16_kernel(const float* __restrict__ in, u16* __restrict__ out, int n)
{
    int i = (blockIdx.x * 256 + threadIdx.x) * 8;
    if (i >= n) return;
    float4 v0 = *(const float4*)&in[i];
    float4 v1 = *(const float4*)&in[i + 4];
    union { u16 u[8]; uint4 p; } r;
    r.u[0] = f2b(v0.x); r.u[1] = f2b(v0.y); r.u[2] = f2b(v0.z); r.u[3] = f2b(v0.w);
    r.u[4] = f2b(v1.x); r.u[5] = f2b(v1.y); r.u[6] = f2b(v1.z); r.u[7] = f2b(v1.w);
    *(uint4*)&out[i] = r.p;
}

// ---------------------------------------------------------------------------
// Both weight transposes in ONE launch.  z=0: Wqkv[768,2304] -> WqkvT;
// z=1: Wproj[768,768] -> WprojT.  64x64 tiles; z=1 blocks with bx>=12 exit.
// ---------------------------------------------------------------------------
__global__ __launch_bounds__(256)
void transpose2_bf16_kernel(const float* __restrict__ Wq, u16* __restrict__ WqT,
                            const float* __restrict__ Wp, u16* __restrict__ WpT)
{
    const int z = blockIdx.z;
    if (z == 1 && blockIdx.x >= Dn / 64) return;
    const float* W  = z ? Wp : Wq;
    u16* WT         = z ? WpT : WqT;
    const int N     = z ? Dn : D3;
    const int K     = Dn;

    __shared__ float Ls[64][65];
    const int bk = blockIdx.y * 64, bn = blockIdx.x * 64;
    const int r  = threadIdx.x >> 2;
    const int c0 = (threadIdx.x & 3) * 16;
    #pragma unroll
    for (int i = 0; i < 4; ++i) {
        float4 v = *(const float4*)&W[(size_t)(bk + r) * N + bn + c0 + i * 4];
        Ls[r][c0 + i * 4 + 0] = v.x;
        Ls[r][c0 + i * 4 + 1] = v.y;
        Ls[r][c0 + i * 4 + 2] = v.z;
        Ls[r][c0 + i * 4 + 3] = v.w;
    }
    __syncthreads();
    #pragma unroll
    for (int i = 0; i < 16; ++i) {
        WT[(size_t)(bn + r) * K + bk + c0 + i] = f2b(Ls[c0 + i][r]);
    }
}

// ---------------------------------------------------------------------------
// bf16 MFMA GEMM, 128x128 tile, BK=64, stage-early double-buffered (the
// round-14-verified proj structure, now templated on MODE). 64 KB LDS
// (2 blocks/CU, 8 waves/CU). Per barrier period: 32 MFMA + 16 ds_read per
// wave -- covers the stage latency that BK32's shorter period exposes
// (measured: proj ~1.25x faster than BK32 at equal traffic).
// LDS layout: 64-elem rows, octet swizzle o^(row&7) (attn-verified).
// 1D grid, XCD-chunked bijective swizzle (nwg%8==0).
// MODE 0: fp32 C + bias.  MODE 1 (QKV): cols<1536 -> bf16 qkv;
// cols>=1536 -> V transposed into VT[b,h,d,t] (packed 4-row 8B stores).
// ---------------------------------------------------------------------------
template <int MODE>
__global__ __launch_bounds__(256)
void gemm_bk64_kernel(const u16* __restrict__ A, const u16* __restrict__ BT,
                      const float* __restrict__ bias, void* __restrict__ Cout,
                      u16* __restrict__ VTout, int M, int N, int K)
{
    __shared__ u16 As[2][128 * 64];   // 16 KB per buffer
    __shared__ u16 Bs[2][128 * 64];
    const int tid  = threadIdx.x;
    const int w    = tid >> 6;
    const int lane = tid & 63;
    const int li   = lane & 15;
    const int g    = lane >> 4;
    const int wm   = w >> 1, wn = w & 1;

    const int fid = blockIdx.x;
    const int wg  = (fid & 7) * ((int)gridDim.x >> 3) + (fid >> 3);
    const int nbx = N / 128;
    const int bm  = (wg / nbx) * 128;
    const int bn  = (wg % nbx) * 128;

    // stage: 1024 chunks per matrix, 4/thread each. Chunk L: row = L>>3,
    // slot s = L&7 holds global octet s^(row&7) of row.
#define GSTAGE64(k0s, buf_) do {                                               \
        _Pragma("unroll")                                                      \
        for (int i_ = 0; i_ < 4; ++i_) {                                       \
            const int L_   = i_ * 256 + tid;                                   \
            const int row_ = L_ >> 3;                                          \
            const int gp_  = (L_ & 7) ^ (row_ & 7);                            \
            async_lds16(&As[buf_][(i_ * 256 + w * 64) * 8],                    \
                        &A[(size_t)(bm + row_) * K + (k0s) + gp_ * 8]);        \
            async_lds16(&Bs[buf_][(i_ * 256 + w * 64) * 8],                    \
                        &BT[(size_t)(bn + row_) * K + (k0s) + gp_ * 8]);       \
        }                                                                      \
    } while (0)

    f32x4 acc[4][4];
    #pragma unroll
    for (int i = 0; i < 4; ++i)
        #pragma unroll
        for (int j = 0; j < 4; ++j)
            acc[i][j] = (f32x4){0.f, 0.f, 0.f, 0.f};

    GSTAGE64(0, 0);
    __syncthreads();

    const int nk = K / 64;   // 12
    for (int kt = 0; kt < nk; ++kt) {
        const int cur = kt & 1;
        if (kt + 1 < nk) GSTAGE64((kt + 1) * 64, cur ^ 1);

        #pragma unroll
        for (int kk = 0; kk < 2; ++kk) {
            bf16x8 af[4], bfr[4];
            #pragma unroll
            for (int fm = 0; fm < 4; ++fm) {
                const int row = wm * 64 + fm * 16 + li;
                af[fm] = *(const bf16x8*)&As[cur][
                    row * 64 + ((kk * 32 + g * 8) ^ ((li & 7) * 8))];
            }
            #pragma unroll
            for (int fn = 0; fn < 4; ++fn) {
                const int row = wn * 64 + fn * 16 + li;
                bfr[fn] = *(const bf16x8*)&Bs[cur][
                    row * 64 + ((kk * 32 + g * 8) ^ ((li & 7) * 8))];
            }
            __builtin_amdgcn_s_setprio(1);
            #pragma unroll
            for (int fm = 0; fm < 4; ++fm)
                #pragma unroll
                for (int fn = 0; fn < 4; ++fn)
                    acc[fm][fn] = __builtin_amdgcn_mfma_f32_16x16x32_bf16(
                        af[fm], bfr[fn], acc[fm][fn], 0, 0, 0);
            __builtin_amdgcn_s_setprio(0);
        }

        __syncthreads();
    }
#undef GSTAGE64

    if (MODE == 1 && bn >= 2 * Dn) {
        // V tile -> VT[b,h,d,t], 4 consecutive t rows packed per 8B store
        #pragma unroll
        for (int fm = 0; fm < 4; ++fm) {
            const int t0g = bm + wm * 64 + fm * 16 + g * 4;
            const int bb = t0g >> 10, tt = t0g & 1023;
            #pragma unroll
            for (int fn = 0; fn < 4; ++fn) {
                const int ncol = bn + wn * 64 + fn * 16 + li;
                const float bs = bias[ncol];
                const int cv = ncol - 2 * Dn;
                const int hv = cv >> 6, dv = cv & 63;
                union { u16 u[4]; uint2 p; } r;
                #pragma unroll
                for (int reg = 0; reg < 4; ++reg)
                    r.u[reg] = f2b(acc[fm][fn][reg] + bs);
                *(uint2*)&VTout[(((size_t)bb * Hn + hv) * HDn + dv) * Tn + tt] = r.p;
            }
        }
    } else {
        #pragma unroll
        for (int fm = 0; fm < 4; ++fm) {
            #pragma unroll
            for (int reg = 0; reg < 4; ++reg) {
                const size_t row = (size_t)(bm + wm * 64 + fm * 16 + g * 4 + reg);
                #pragma unroll
                for (int fn = 0; fn < 4; ++fn) {
                    const int col = bn + wn * 64 + fn * 16 + li;
                    const float v = acc[fm][fn][reg] + bias[col];
                    if (MODE == 1) ((u16*)Cout)[row * N + col] = f2b(v);
                    else           ((float*)Cout)[row * N + col] = v;
                }
            }
        }
    }
}

// ---------------------------------------------------------------------------
// LDS-staged MFMA flash attention (causal), swapped QK^T.  (round-7 verified)
// ---------------------------------------------------------------------------
__global__ __launch_bounds__(256, 3)
void attn_mfma_kernel(const u16* __restrict__ qkvb, const u16* __restrict__ VT,
                      u16* __restrict__ attnb)
{
    __shared__ u16 Ks[2][64 * 64];
    __shared__ u16 Vs[2][64 * 64];
    __shared__ u16 Pb[4][32 * 64];

    const int tid  = threadIdx.x;
    const int w    = tid >> 6;
    const int lane = tid & 63;
    const int li   = lane & 15;
    const int g    = lane >> 4;

    const int fid = blockIdx.x;
    const int xcd = fid & 7, j = fid >> 3;
    const int bh  = xcd + 8 * (j % 12);
    const int qt  = 7 - (j / 12);
    const int b   = bh / 12, h = bh % 12;

    const int q0   = qt * 128;
    const int wrow = q0 + w * 32;
    const size_t rowbase = (size_t)b * Tn;
    const u16* vbase = VT + (size_t)bh * HDn * Tn;
    const u16* kbase = &qkvb[rowbase * D3 + Dn + h * HDn];

#define STAGE(kt_, buf_) do {                                                  \
        const int k0s = (kt_) * 64;                                            \
        _Pragma("unroll")                                                      \
        for (int i_ = 0; i_ < 2; ++i_) {                                       \
            const int L_   = i_ * 256 + tid;                                   \
            const int row_ = L_ >> 3;                                          \
            const int gp_  = (L_ & 7) ^ (row_ & 7);                            \
            async_lds16(&Ks[buf_][(i_ * 256 + w * 64) * 8],                    \
                        &kbase[(size_t)(k0s + row_) * D3 + gp_ * 8]);          \
            async_lds16(&Vs[buf_][(i_ * 256 + w * 64) * 8],                    \
                        &vbase[(size_t)row_ * Tn + k0s + gp_ * 8]);            \
        }                                                                      \
    } while (0)

    STAGE(0, 0);

    bf16x8 qf[2][2];
    #pragma unroll
    for (int rh = 0; rh < 2; ++rh)
        #pragma unroll
        for (int kc = 0; kc < 2; ++kc)
            qf[rh][kc] = *(const bf16x8*)&qkvb[
                (rowbase + wrow + rh * 16 + li) * D3 + h * HDn + kc * 32 + g * 8];

    f32x4 of[2][4];
    float m_run[2], l_run[2];
    #pragma unroll
    for (int rh = 0; rh < 2; ++rh) {
        #pragma unroll
        for (int nf = 0; nf < 4; ++nf) of[rh][nf] = (f32x4){0.f, 0.f, 0.f, 0.f};
        m_run[rh] = -1e30f;
        l_run[rh] = 0.f;
    }

    const int nkt   = (q0 >> 6) + 2;
    const int myend = wrow >> 6;

    __syncthreads();

    for (int kt = 0; kt < nkt; ++kt) {
        const int cur = kt & 1;
        if (kt + 1 < nkt) STAGE(kt + 1, cur ^ 1);

        if (kt <= myend) {
            const int k0 = kt * 64;
            const bool maskit = (kt == myend);

            f32x4 st[2][4];
            #pragma unroll
            for (int rh = 0; rh < 2; ++rh)
                #pragma unroll
                for (int nf = 0; nf < 4; ++nf) st[rh][nf] = (f32x4){0.f, 0.f, 0.f, 0.f};
            __builtin_amdgcn_s_setprio(1);
            #pragma unroll
            for (int kc = 0; kc < 2; ++kc)
                #pragma unroll
                for (int nf = 0; nf < 4; ++nf) {
                    const bf16x8 kf = *(const bf16x8*)&Ks[cur][
                        (nf * 16 + li) * 64 + ((kc * 32 + g * 8) ^ ((li & 7) * 8))];
                    st[0][nf] = __builtin_amdgcn_mfma_f32_16x16x32_bf16(kf, qf[0][kc], st[0][nf], 0, 0, 0);
                    st[1][nf] = __builtin_amdgcn_mfma_f32_16x16x32_bf16(kf, qf[1][kc], st[1][nf], 0, 0, 0);
                }
            __builtin_amdgcn_s_setprio(0);

            #pragma unroll
            for (int rh = 0; rh < 2; ++rh) {
                if (maskit) {
                    const int qg = wrow + rh * 16 + li;
                    #pragma unroll
                    for (int nf = 0; nf < 4; ++nf)
                        #pragma unroll
                        for (int reg = 0; reg < 4; ++reg)
                            if (k0 + nf * 16 + g * 4 + reg > qg) st[rh][nf][reg] = -1e30f;
                }

                float mt = st[rh][0][0];
                #pragma unroll
                for (int nf = 0; nf < 4; ++nf)
                    #pragma unroll
                    for (int reg = 0; reg < 4; ++reg)
                        mt = fmaxf(mt, st[rh][nf][reg]);
                mt = fmaxf(mt, __shfl_xor(mt, 16, 64));
                mt = fmaxf(mt, __shfl_xor(mt, 32, 64));
                const float mts = mt * SM_SCALE;

                const float mold = m_run[rh];
                if (!__all(mts <= mold + 8.0f)) {
                    const float mnew = fmaxf(mold, mts);
                    const float resc = exp2f(mold - mnew);
                    m_run[rh] = mnew;
                    l_run[rh] *= resc;
                    float rs[4];
                    #pragma unroll
                    for (int reg = 0; reg < 4; ++reg)
                        rs[reg] = __shfl(resc, g * 4 + reg, 64);
                    #pragma unroll
                    for (int nf = 0; nf < 4; ++nf)
                        #pragma unroll
                        for (int reg = 0; reg < 4; ++reg)
                            of[rh][nf][reg] *= rs[reg];
                }

                const float mcur = m_run[rh];
                float ls = 0.f;
                u16* pb = &Pb[w][(rh * 16 + li) * 64];
                #pragma unroll
                for (int nf = 0; nf < 4; ++nf) {
                    const float p0 = exp2f(fmaf(st[rh][nf][0], SM_SCALE, -mcur));
                    const float p1 = exp2f(fmaf(st[rh][nf][1], SM_SCALE, -mcur));
                    const float p2 = exp2f(fmaf(st[rh][nf][2], SM_SCALE, -mcur));
                    const float p3 = exp2f(fmaf(st[rh][nf][3], SM_SCALE, -mcur));
                    ls += (p0 + p1) + (p2 + p3);
                    uint2 pk;
                    pk.x = cvt_pk_bf16(p0, p1);
                    pk.y = cvt_pk_bf16(p2, p3);
                    *(uint2*)&pb[(nf * 16 + g * 4) ^ ((li & 7) << 3)] = pk;
                }
                ls += __shfl_xor(ls, 16, 64);
                ls += __shfl_xor(ls, 32, 64);
                l_run[rh] += ls;
            }

            #pragma unroll
            for (int kc = 0; kc < 2; ++kc) {
                const int pcol = (kc * 32 + g * 8) ^ ((li & 7) << 3);
                const bf16x8 pf0 = *(const bf16x8*)&Pb[w][li * 64 + pcol];
                const bf16x8 pf1 = *(const bf16x8*)&Pb[w][(16 + li) * 64 + pcol];
                __builtin_amdgcn_s_setprio(1);
                #pragma unroll
                for (int nf = 0; nf < 4; ++nf) {
                    const bf16x8 vf = *(const bf16x8*)&Vs[cur][
                        (nf * 16 + li) * 64 + ((kc * 32 + g * 8) ^ ((li & 7) * 8))];
                    of[0][nf] = __builtin_amdgcn_mfma_f32_16x16x32_bf16(pf0, vf, of[0][nf], 0, 0, 0);
                    of[1][nf] = __builtin_amdgcn_mfma_f32_16x16x32_bf16(pf1, vf, of[1][nf], 0, 0, 0);
                }
                __builtin_amdgcn_s_setprio(0);
            }
        }

        __syncthreads();
    }
#undef STAGE

    #pragma unroll
    for (int rh = 0; rh < 2; ++rh) {
        const float inv = 1.0f / l_run[rh];
        float rs[4];
        #pragma unroll
        for (int reg = 0; reg < 4; ++reg)
            rs[reg] = __shfl(inv, g * 4 + reg, 64);
        #pragma unroll
        for (int reg = 0; reg < 4; ++reg) {
            const size_t row = rowbase + wrow + rh * 16 + g * 4 + reg;
            #pragma unroll
            for (int nf = 0; nf < 4; ++nf)
                attnb[row * Dn + h * HDn + nf * 16 + li] = f2b(of[rh][nf][reg] * rs[reg]);
        }
    }
}

extern "C" void kernel_launch(void* const* d_in, const int* in_sizes, int n_in,
                              void* d_out, int out_size, void* d_ws, size_t ws_size,
                              hipStream_t stream) {
    const float* x     = (const float*)d_in[0];
    const float* Wqkv  = (const float*)d_in[1];
    const float* bqkv  = (const float*)d_in[2];
    const float* Wproj = (const float*)d_in[3];
    const float* bproj = (const float*)d_in[4];
    float* out = (float*)d_out;

    const int M = Bn * Tn;   // 8192

    char* ws = (char*)d_ws;
    u16* qkvb   = (u16*)ws;  ws += (size_t)M * D3 * 2;        // 37.75 MB
    u16* xb     = (u16*)ws;  ws += (size_t)M * Dn * 2;        // 12.6 MB
    u16* attnb  = (u16*)ws;  ws += (size_t)M * Dn * 2;        // 12.6 MB
    u16* VT     = (u16*)ws;  ws += (size_t)Bn * Hn * HDn * Tn * 2; // 12.6 MB
    u16* WqkvT  = (u16*)ws;  ws += (size_t)D3 * Dn * 2;       // 3.5 MB
    u16* WprojT = (u16*)ws;                                   // 1.2 MB

    conv_bf16_kernel<<<M * Dn / 8 / 256, 256, 0, stream>>>(x, xb, M * Dn);
    {
        dim3 g(D3 / 64, Dn / 64, 2);
        transpose2_bf16_kernel<<<g, 256, 0, stream>>>(Wqkv, WqkvT, Wproj, WprojT);
    }
    {
        const int nwg = (M / 128) * (D3 / 128);   // 1152, %8==0
        gemm_bk64_kernel<1><<<nwg, 256, 0, stream>>>(
            xb, WqkvT, bqkv, qkvb, VT, M, D3, Dn);
    }
    attn_mfma_kernel<<<768, 256, 0, stream>>>(qkvb, VT, attnb);
    {
        const int nwg = (M / 128) * (Dn / 128);   // 384, %8==0
        gemm_bk64_kernel<0><<<nwg, 256, 0, stream>>>(
            attnb, WprojT, bproj, out, nullptr, M, Dn, Dn);
    }
}